// Round 5
// baseline (294.786 us; speedup 1.0000x reference)
//
#include <hip/hip_runtime.h>

#define VOCAB 128
#define EMB   8
#define HID   32
#define BATCH 512
#define SEQ   512
#define G4    128   // 4*HID
#define KB    8     // recurrence steps per store-flush phase

#define LOG2E 1.4426950408889634f

// ---------------------------------------------------------------------------
// Kernel 1: proj[v][r] = (dot(emb[v], w_ih[r]) + b_ih[r] + b_hh[r]) * rowscale
// rowscale folds the exp->exp2 conversion into the preactivation:
//   g-rows [64,96): 2*log2e   (tanh uses exp(2x) = exp2(2*log2e*x))
//   others        :   log2e   (sigmoid uses exp(-x) = exp2(-log2e*x))
// ---------------------------------------------------------------------------
__global__ void build_proj(const float* __restrict__ emb,
                           const float* __restrict__ w_ih,
                           const float* __restrict__ b_ih,
                           const float* __restrict__ b_hh,
                           float* __restrict__ proj) {
    int idx = blockIdx.x * blockDim.x + threadIdx.x;   // 0 .. 16383
    int v = idx >> 7;
    int r = idx & 127;
    float acc = b_ih[r] + b_hh[r];
#pragma unroll
    for (int e = 0; e < EMB; ++e)
        acc += emb[v * EMB + e] * w_ih[r * EMB + e];
    float sc = (r >= 64 && r < 96) ? (2.0f * LOG2E) : LOG2E;
    proj[v * G4 + r] = acc * sc;
}

// ---------------------------------------------------------------------------
// Fast gate nonlinearities: single v_exp_f32 + single v_rcp_f32.
// Inputs are pre-scaled by log2e (sig) / 2*log2e (tanh).
// ---------------------------------------------------------------------------
__device__ __forceinline__ float sig2(float x) {      // x = log2e * preact
    return __builtin_amdgcn_rcpf(1.0f + __builtin_amdgcn_exp2f(-x));
}
__device__ __forceinline__ float tanh2(float x2) {    // x2 = 2*log2e * preact
    return 1.0f - 2.0f * __builtin_amdgcn_rcpf(__builtin_amdgcn_exp2f(x2) + 1.0f);
}

// ---------------------------------------------------------------------------
// Kernel 2: LSTM recurrence. One wave handles TWO sequences, interleaved per
// step: the two chains are independent, so sequence B's FMA issue hides
// sequence A's transcendental latency and vice versa (1 wave/SIMD otherwise
// has nothing to overlap with).
//  - proj staged in LDS (no global loads in the loop)
//  - weights pinned in VGPRs, pre-scaled by log2e per gate row
//  - h broadcast via v_readlane; halves swapped via v_permlane32_swap_b32
//  - h replicated in both lane halves -> lo lanes store seq A, hi lanes seq B
// ---------------------------------------------------------------------------
__global__ __launch_bounds__(64)
__attribute__((amdgpu_waves_per_eu(1, 1)))
void lstm_rec(
    const int*   __restrict__ tokens,   // [B][T]
    const float* __restrict__ w_hh,     // [128][32]
    const float* __restrict__ proj,     // [128][128], pre-scaled
    float*       __restrict__ h_out)    // [B*T][32]
{
    const int b    = blockIdx.x;        // 0..255 -> sequences 2b, 2b+1
    const int lane = threadIdx.x;       // 0..63

    __shared__ float sproj[VOCAB * G4];   // 64 KB

    // ---- stage proj into LDS ----
    {
        const float4* src = (const float4*)proj;
        float4*       dst = (float4*)sproj;
#pragma unroll 4
        for (int i = 0; i < (VOCAB * G4 / 4) / 64; ++i)
            dst[i * 64 + lane] = src[i * 64 + lane];
    }

    // ---- recurrent weights, pre-scaled, pinned resident ----
    // w0: row lane      (i-rows lane<32, f-rows lane>=32) -> *log2e
    // w1: row lane+64   (g-rows lane<32 -> *2log2e, o-rows -> *log2e)
    const float sc1 = (lane < 32) ? (2.0f * LOG2E) : LOG2E;
    float w0[HID], w1[HID];
#pragma unroll
    for (int j = 0; j < HID; ++j) {
        w0[j] = w_hh[lane * HID + j] * LOG2E;
        w1[j] = w_hh[(lane + 64) * HID + j] * sc1;
    }
#pragma unroll
    for (int j = 0; j < HID; ++j) {
        asm volatile("" : "+v"(w0[j]), "+v"(w1[j]));
    }

    // ---- tokens for both sequences in lane registers ----
    const int* tokA = tokens + (2 * b) * SEQ;
    const int* tokB = tokens + (2 * b + 1) * SEQ;
    int tvA[KB], tvB[KB];
    {
        int4 a0 = ((const int4*)tokA)[lane * 2];
        int4 a1 = ((const int4*)tokA)[lane * 2 + 1];
        tvA[0] = a0.x; tvA[1] = a0.y; tvA[2] = a0.z; tvA[3] = a0.w;
        tvA[4] = a1.x; tvA[5] = a1.y; tvA[6] = a1.z; tvA[7] = a1.w;
        int4 b0 = ((const int4*)tokB)[lane * 2];
        int4 b1 = ((const int4*)tokB)[lane * 2 + 1];
        tvB[0] = b0.x; tvB[1] = b0.y; tvB[2] = b0.z; tvB[3] = b0.w;
        tvB[4] = b1.x; tvB[5] = b1.y; tvB[6] = b1.z; tvB[7] = b1.w;
    }

    __syncthreads();

    float hA = 0.0f, cA = 0.0f, hB = 0.0f, cB = 0.0f;

    // prime step-0 xp
    int tkA0 = __builtin_amdgcn_readlane(tvA[0], 0);
    int tkB0 = __builtin_amdgcn_readlane(tvB[0], 0);
    float xa0 = sproj[tkA0 * G4 + lane];
    float xa1 = sproj[tkA0 * G4 + 64 + lane];
    float xb0 = sproj[tkB0 * G4 + lane];
    float xb1 = sproj[tkB0 * G4 + 64 + lane];

    // store pointers: lo lanes write seq A, hi lanes write seq B
    float* hp = (lane < 32)
        ? (h_out + (size_t)(2 * b)     * SEQ * HID + lane)
        : (h_out + (size_t)(2 * b + 1) * SEQ * HID + (lane - 32));

    float hsA[KB], hsB[KB];

    for (int t0 = 0; t0 < SEQ; t0 += KB) {
#pragma unroll
        for (int k = 0; k < KB; ++k) {
            // ---- prefetch next step's xp from LDS ----
            const int tn  = (t0 + k + 1) & (SEQ - 1);
            const int ln  = tn >> 3;              // uniform (SGPR) lane index
            const int tkA = __builtin_amdgcn_readlane(tvA[(k + 1) & 7], ln);
            const int tkB = __builtin_amdgcn_readlane(tvB[(k + 1) & 7], ln);
            float na0 = sproj[tkA * G4 + lane];
            float na1 = sproj[tkA * G4 + 64 + lane];
            float nb0 = sproj[tkB * G4 + lane];
            float nb1 = sproj[tkB * G4 + 64 + lane];

            // ---- matvec A and B (independent chains, scheduler interleaves) ----
            float sA0 = xa0, sA1 = 0.0f, sA2 = 0.0f, sA3 = 0.0f;
            float uA0 = xa1, uA1 = 0.0f, uA2 = 0.0f, uA3 = 0.0f;
            float sB0 = xb0, sB1 = 0.0f, sB2 = 0.0f, sB3 = 0.0f;
            float uB0 = xb1, uB1 = 0.0f, uB2 = 0.0f, uB3 = 0.0f;
            unsigned ha = __float_as_uint(hA);
            unsigned hbb = __float_as_uint(hB);
#pragma unroll
            for (int j = 0; j < HID; j += 2) {
                float a0 = __uint_as_float(__builtin_amdgcn_readlane(ha,  j));
                float a1 = __uint_as_float(__builtin_amdgcn_readlane(ha,  j + 1));
                float b0 = __uint_as_float(__builtin_amdgcn_readlane(hbb, j));
                float b1 = __uint_as_float(__builtin_amdgcn_readlane(hbb, j + 1));
                sA0 = fmaf(a0, w0[j],     sA0);
                sA1 = fmaf(a1, w0[j + 1], sA1);
                uA0 = fmaf(a0, w1[j],     uA0);
                uA1 = fmaf(a1, w1[j + 1], uA1);
                sB0 = fmaf(b0, w0[j],     sB0);
                sB1 = fmaf(b1, w0[j + 1], sB1);
                uB0 = fmaf(b0, w1[j],     uB0);
                uB1 = fmaf(b1, w1[j + 1], uB1);
                (void)sA2; (void)sA3; (void)uA2; (void)uA3;
                (void)sB2; (void)sB3; (void)uB2; (void)uB3;
            }
            float accA0 = sA0 + sA1;   // i (lo) | f (hi), *log2e
            float accA1 = uA0 + uA1;   // g (lo, *2log2e) | o (hi, *log2e)
            float accB0 = sB0 + sB1;
            float accB1 = uB0 + uB1;

            // ---- swap halves so every lane holds all four gates ----
            float ivA = accA0, fvA = accA0;
            asm("v_permlane32_swap_b32 %0, %1" : "+v"(ivA), "+v"(fvA));
            float gvA = accA1, ovA = accA1;
            asm("v_permlane32_swap_b32 %0, %1" : "+v"(gvA), "+v"(ovA));
            float ivB = accB0, fvB = accB0;
            asm("v_permlane32_swap_b32 %0, %1" : "+v"(ivB), "+v"(fvB));
            float gvB = accB1, ovB = accB1;
            asm("v_permlane32_swap_b32 %0, %1" : "+v"(gvB), "+v"(ovB));

            // ---- nonlinearities (exp2-domain, hw rcp) ----
            cA = sig2(fvA) * cA + sig2(ivA) * tanh2(gvA);
            hA = sig2(ovA) * tanh2(cA * (2.0f * LOG2E));
            cB = sig2(fvB) * cB + sig2(ivB) * tanh2(gvB);
            hB = sig2(ovB) * tanh2(cB * (2.0f * LOG2E));

            hsA[k] = hA;
            hsB[k] = hB;

            xa0 = na0; xa1 = na1;
            xb0 = nb0; xb1 = nb1;
        }

        // ---- flush: lo half stores seq A, hi half stores seq B ----
#pragma unroll
        for (int k = 0; k < KB; ++k) {
            float hv = (lane < 32) ? hsA[k] : hsB[k];
            hp[(size_t)(t0 + k) * HID] = hv;
        }
    }
}

// ---------------------------------------------------------------------------
// Kernel 3: logits[pos][v] = h[pos] . w_out[v] + b_out[v]
// ---------------------------------------------------------------------------
#define POS_PER_WAVE 16

__global__ __launch_bounds__(256) void out_proj(
    const float* __restrict__ h,      // [B*T][32]
    const float* __restrict__ w_out,  // [128][32]
    const float* __restrict__ b_out,  // [128]
    float*       __restrict__ out)    // [B*T][128]
{
    const int gtid = blockIdx.x * blockDim.x + threadIdx.x;
    const int wave = gtid >> 6;
    const int lane = threadIdx.x & 63;

    float wv0[HID], wv1[HID];
#pragma unroll
    for (int j = 0; j < HID; ++j) {
        wv0[j] = w_out[lane * HID + j];
        wv1[j] = w_out[(lane + 64) * HID + j];
    }
    const float bb0 = b_out[lane];
    const float bb1 = b_out[lane + 64];

    int pos0 = wave * POS_PER_WAVE;
    for (int p = 0; p < POS_PER_WAVE; ++p) {
        int pos = __builtin_amdgcn_readfirstlane(pos0 + p);
        const float* hp = h + (size_t)pos * HID;
        float a0 = bb0, a1 = bb1;
#pragma unroll
        for (int j4 = 0; j4 < HID / 4; ++j4) {
            float4 hv = *reinterpret_cast<const float4*>(hp + 4 * j4);
            a0 = fmaf(hv.x, wv0[4 * j4 + 0], a0);
            a1 = fmaf(hv.x, wv1[4 * j4 + 0], a1);
            a0 = fmaf(hv.y, wv0[4 * j4 + 1], a0);
            a1 = fmaf(hv.y, wv1[4 * j4 + 1], a1);
            a0 = fmaf(hv.z, wv0[4 * j4 + 2], a0);
            a1 = fmaf(hv.z, wv1[4 * j4 + 2], a1);
            a0 = fmaf(hv.w, wv0[4 * j4 + 3], a0);
            a1 = fmaf(hv.w, wv1[4 * j4 + 3], a1);
        }
        out[(size_t)pos * VOCAB + lane]      = a0;
        out[(size_t)pos * VOCAB + 64 + lane] = a1;
    }
}

// ---------------------------------------------------------------------------
extern "C" void kernel_launch(void* const* d_in, const int* in_sizes, int n_in,
                              void* d_out, int out_size, void* d_ws, size_t ws_size,
                              hipStream_t stream) {
    const int*   tokens = (const int*)  d_in[0];
    const float* emb    = (const float*)d_in[1];
    const float* w_ih   = (const float*)d_in[2];
    const float* w_hh   = (const float*)d_in[3];
    const float* b_ih   = (const float*)d_in[4];
    const float* b_hh   = (const float*)d_in[5];
    const float* w_out  = (const float*)d_in[6];
    const float* b_out  = (const float*)d_in[7];
    float*       out    = (float*)d_out;

    float* proj = (float*)d_ws;
    float* hbuf = (float*)((char*)d_ws + VOCAB * G4 * sizeof(float));

    build_proj<<<(VOCAB * G4) / 256, 256, 0, stream>>>(emb, w_ih, b_ih, b_hh, proj);

    lstm_rec<<<BATCH / 2, 64, 0, stream>>>(tokens, w_hh, proj, hbuf);

    const int total_pos = BATCH * SEQ;                    // 262144
    const int waves     = total_pos / POS_PER_WAVE;       // 16384
    out_proj<<<waves / 4, 256, 0, stream>>>(hbuf, w_out, b_out, out);
}

// Round 10
// 195.722 us; speedup vs baseline: 1.5061x; 1.5061x over previous
//
#include <hip/hip_runtime.h>

#define VOCAB 128
#define EMB   8
#define HID   32
#define BATCH 512
#define SEQ   512
#define G4    128   // 4*HID
#define KB    8     // recurrence steps per store-flush phase

#define LOG2E 1.4426950408889634f

// ---------------------------------------------------------------------------
// Kernel 1: proj[v][r] = (dot(emb[v], w_ih[r]) + b_ih[r] + b_hh[r]) * rowscale
// rowscale folds exp->exp2: g-rows [64,96): 2*log2e ; others: log2e
// ---------------------------------------------------------------------------
__global__ void build_proj(const float* __restrict__ emb,
                           const float* __restrict__ w_ih,
                           const float* __restrict__ b_ih,
                           const float* __restrict__ b_hh,
                           float* __restrict__ proj) {
    int idx = blockIdx.x * blockDim.x + threadIdx.x;   // 0 .. 16383
    int v = idx >> 7;
    int r = idx & 127;
    float acc = b_ih[r] + b_hh[r];
#pragma unroll
    for (int e = 0; e < EMB; ++e)
        acc += emb[v * EMB + e] * w_ih[r * EMB + e];
    float sc = (r >= 64 && r < 96) ? (2.0f * LOG2E) : LOG2E;
    proj[v * G4 + r] = acc * sc;
}

// ---------------------------------------------------------------------------
// Fast gate nonlinearities (inputs pre-scaled by log2e / 2*log2e).
// ---------------------------------------------------------------------------
__device__ __forceinline__ float sig2(float x) {
    return __builtin_amdgcn_rcpf(1.0f + __builtin_amdgcn_exp2f(-x));
}
__device__ __forceinline__ float tanh2(float x2) {
    return 1.0f - 2.0f * __builtin_amdgcn_rcpf(__builtin_amdgcn_exp2f(x2) + 1.0f);
}

// ---------------------------------------------------------------------------
// Half-broadcast via permlane32_swap, ALIAS-PROOF:
// two early-clobber outputs are guaranteed distinct registers (distinct from
// the input too); copies happen inside the asm. Semantics (established by the
// passing R2-R5 builds): after swap, 'lo' holds the low-half value broadcast
// to all 64 lanes, 'hi' holds the high-half value broadcast to all 64 lanes.
// ---------------------------------------------------------------------------
__device__ __forceinline__ void half_bcast(float acc, float& lo, float& hi) {
    asm("v_mov_b32 %0, %2\n\t"
        "v_mov_b32 %1, %2\n\t"
        "v_permlane32_swap_b32 %0, %1"
        : "=&v"(lo), "=&v"(hi)
        : "v"(acc));
}

// ---------------------------------------------------------------------------
// Kernel 2: LSTM recurrence — R4's proven structure (LDS-staged proj, pinned
// weights, per-step rolling prefetch, KB=8 store flush) + R5's proven
// arithmetic (pre-scaled weights, exp2/rcp nonlinearities) + alias-proof
// half-broadcast.
// ---------------------------------------------------------------------------
__global__ __launch_bounds__(64)
__attribute__((amdgpu_waves_per_eu(1, 1)))
void lstm_rec(
    const int*   __restrict__ tokens,   // [B][T]
    const float* __restrict__ w_hh,     // [128][32]
    const float* __restrict__ proj,     // [128][128], pre-scaled
    float*       __restrict__ h_out)    // [B*T][32]
{
    const int b    = blockIdx.x;
    const int lane = threadIdx.x;      // 0..63

    __shared__ float sproj[VOCAB * G4];   // 64 KB

    // ---- stage proj into LDS (once) ----
    {
        const float4* src = (const float4*)proj;
        float4*       dst = (float4*)sproj;
#pragma unroll 4
        for (int i = 0; i < (VOCAB * G4 / 4) / 64; ++i)
            dst[i * 64 + lane] = src[i * 64 + lane];
    }

    // ---- recurrent weights: 2 gate rows per lane, pre-scaled, pinned ----
    const float sc1 = (lane < 32) ? (2.0f * LOG2E) : LOG2E;
    float w0[HID], w1[HID];
#pragma unroll
    for (int j = 0; j < HID; ++j) {
        w0[j] = w_hh[lane * HID + j] * LOG2E;
        w1[j] = w_hh[(lane + 64) * HID + j] * sc1;
    }
#pragma unroll
    for (int j = 0; j < HID; ++j) {
        asm volatile("" : "+v"(w0[j]), "+v"(w1[j]));   // non-rematerializable
    }

    // ---- all 512 tokens of this sequence in lane registers ----
    // lane l holds tok[l*8 .. l*8+7]
    const int* tok = tokens + b * SEQ;
    int tv[KB];
    {
        int4 a = ((const int4*)tok)[lane * 2];
        int4 d = ((const int4*)tok)[lane * 2 + 1];
        tv[0] = a.x; tv[1] = a.y; tv[2] = a.z; tv[3] = a.w;
        tv[4] = d.x; tv[5] = d.y; tv[6] = d.z; tv[7] = d.w;
    }

    __syncthreads();

    float h = 0.0f, c = 0.0f;

    // prime step-0 xp from LDS
    int tk0 = __builtin_amdgcn_readlane(tv[0], 0);
    float xc0 = sproj[tk0 * G4 + lane];
    float xc1 = sproj[tk0 * G4 + 64 + lane];

    float* hp = h_out + (size_t)b * SEQ * HID + lane;   // lanes<32 store
    float hsave[KB];

    for (int t0 = 0; t0 < SEQ; t0 += KB) {
#pragma unroll
        for (int k = 0; k < KB; ++k) {
            // ---- prefetch next step's xp from LDS (1 step ahead) ----
            const int tn   = (t0 + k + 1) & (SEQ - 1);
            const int tkn  = __builtin_amdgcn_readlane(tv[(k + 1) & 7], tn >> 3);
            float xn0 = sproj[tkn * G4 + lane];
            float xn1 = sproj[tkn * G4 + 64 + lane];

            // ---- matvec: 8 independent chains of depth 8 ----
            float s0 = xc0, s1 = 0.0f, s2 = 0.0f, s3 = 0.0f;  // row lane
            float u0 = xc1, u1 = 0.0f, u2 = 0.0f, u3 = 0.0f;  // row lane+64
            unsigned hb = __float_as_uint(h);
#pragma unroll
            for (int j = 0; j < HID; j += 4) {
                float h0 = __uint_as_float(__builtin_amdgcn_readlane(hb, j));
                float h1 = __uint_as_float(__builtin_amdgcn_readlane(hb, j + 1));
                float h2 = __uint_as_float(__builtin_amdgcn_readlane(hb, j + 2));
                float h3 = __uint_as_float(__builtin_amdgcn_readlane(hb, j + 3));
                s0 = fmaf(h0, w0[j],     s0);
                s1 = fmaf(h1, w0[j + 1], s1);
                s2 = fmaf(h2, w0[j + 2], s2);
                s3 = fmaf(h3, w0[j + 3], s3);
                u0 = fmaf(h0, w1[j],     u0);
                u1 = fmaf(h1, w1[j + 1], u1);
                u2 = fmaf(h2, w1[j + 2], u2);
                u3 = fmaf(h3, w1[j + 3], u3);
            }
            float acc0 = (s0 + s1) + (s2 + s3);  // i (lo lanes) | f (hi lanes)
            float acc1 = (u0 + u1) + (u2 + u3);  // g (lo, *2log2e) | o (hi)

            // ---- alias-proof half broadcast: iv/gv = lo, fv/ov = hi ----
            float iv, fv, gv, ov;
            half_bcast(acc0, iv, fv);
            half_bcast(acc1, gv, ov);

            // ---- nonlinearities (exp2-domain, hw rcp) ----
            c = sig2(fv) * c + sig2(iv) * tanh2(gv);
            h = sig2(ov) * tanh2(c * (2.0f * LOG2E));

            hsave[k] = h;

            xc0 = xn0;
            xc1 = xn1;
        }

        // ---- flush h stores; nothing in the loop waits on vmcnt ----
        if (lane < 32) {
#pragma unroll
            for (int k = 0; k < KB; ++k)
                hp[(size_t)(t0 + k) * HID] = hsave[k];
        }
    }
}

// ---------------------------------------------------------------------------
// Kernel 3: logits[pos][v] = h[pos] . w_out[v] + b_out[v]   (R1-R5 proven)
// ---------------------------------------------------------------------------
#define POS_PER_WAVE 16

__global__ __launch_bounds__(256) void out_proj(
    const float* __restrict__ h,      // [B*T][32]
    const float* __restrict__ w_out,  // [128][32]
    const float* __restrict__ b_out,  // [128]
    float*       __restrict__ out)    // [B*T][128]
{
    const int gtid = blockIdx.x * blockDim.x + threadIdx.x;
    const int wave = gtid >> 6;
    const int lane = threadIdx.x & 63;

    float wv0[HID], wv1[HID];
#pragma unroll
    for (int j = 0; j < HID; ++j) {
        wv0[j] = w_out[lane * HID + j];
        wv1[j] = w_out[(lane + 64) * HID + j];
    }
    const float bb0 = b_out[lane];
    const float bb1 = b_out[lane + 64];

    int pos0 = wave * POS_PER_WAVE;
    for (int p = 0; p < POS_PER_WAVE; ++p) {
        int pos = __builtin_amdgcn_readfirstlane(pos0 + p);
        const float* hp = h + (size_t)pos * HID;
        float a0 = bb0, a1 = bb1;
#pragma unroll
        for (int j4 = 0; j4 < HID / 4; ++j4) {
            float4 hv = *reinterpret_cast<const float4*>(hp + 4 * j4);
            a0 = fmaf(hv.x, wv0[4 * j4 + 0], a0);
            a1 = fmaf(hv.x, wv1[4 * j4 + 0], a1);
            a0 = fmaf(hv.y, wv0[4 * j4 + 1], a0);
            a1 = fmaf(hv.y, wv1[4 * j4 + 1], a1);
            a0 = fmaf(hv.z, wv0[4 * j4 + 2], a0);
            a1 = fmaf(hv.z, wv1[4 * j4 + 2], a1);
            a0 = fmaf(hv.w, wv0[4 * j4 + 3], a0);
            a1 = fmaf(hv.w, wv1[4 * j4 + 3], a1);
        }
        out[(size_t)pos * VOCAB + lane]      = a0;
        out[(size_t)pos * VOCAB + 64 + lane] = a1;
    }
}

// ---------------------------------------------------------------------------
extern "C" void kernel_launch(void* const* d_in, const int* in_sizes, int n_in,
                              void* d_out, int out_size, void* d_ws, size_t ws_size,
                              hipStream_t stream) {
    const int*   tokens = (const int*)  d_in[0];
    const float* emb    = (const float*)d_in[1];
    const float* w_ih   = (const float*)d_in[2];
    const float* w_hh   = (const float*)d_in[3];
    const float* b_ih   = (const float*)d_in[4];
    const float* b_hh   = (const float*)d_in[5];
    const float* w_out  = (const float*)d_in[6];
    const float* b_out  = (const float*)d_in[7];
    float*       out    = (float*)d_out;

    float* proj = (float*)d_ws;
    float* hbuf = (float*)((char*)d_ws + VOCAB * G4 * sizeof(float));

    build_proj<<<(VOCAB * G4) / 256, 256, 0, stream>>>(emb, w_ih, b_ih, b_hh, proj);

    lstm_rec<<<BATCH, 64, 0, stream>>>(tokens, w_hh, proj, hbuf);

    const int total_pos = BATCH * SEQ;                    // 262144
    const int waves     = total_pos / POS_PER_WAVE;       // 16384
    out_proj<<<waves / 4, 256, 0, stream>>>(hbuf, w_out, b_out, out);
}

// Round 12
// 189.543 us; speedup vs baseline: 1.5552x; 1.0326x over previous
//
#include <hip/hip_runtime.h>

#define VOCAB 128
#define EMB   8
#define HID   32
#define BATCH 512
#define SEQ   512
#define G4    128   // 4*HID
#define KB    8     // recurrence steps per phase

#define LOG2E 1.4426950408889634f

// ---------------------------------------------------------------------------
// Kernel 1: proj[v][r] = (dot(emb[v], w_ih[r]) + b_ih[r] + b_hh[r]) * rowscale
// rowscale folds exp->exp2: g-rows [64,96): 2*log2e ; others: log2e
// ---------------------------------------------------------------------------
__global__ void build_proj(const float* __restrict__ emb,
                           const float* __restrict__ w_ih,
                           const float* __restrict__ b_ih,
                           const float* __restrict__ b_hh,
                           float* __restrict__ proj) {
    int idx = blockIdx.x * blockDim.x + threadIdx.x;   // 0 .. 16383
    int v = idx >> 7;
    int r = idx & 127;
    float acc = b_ih[r] + b_hh[r];
#pragma unroll
    for (int e = 0; e < EMB; ++e)
        acc += emb[v * EMB + e] * w_ih[r * EMB + e];
    float sc = (r >= 64 && r < 96) ? (2.0f * LOG2E) : LOG2E;
    proj[v * G4 + r] = acc * sc;
}

// ---------------------------------------------------------------------------
// Fast gate nonlinearities (inputs pre-scaled by log2e / 2*log2e). Proven R10.
// ---------------------------------------------------------------------------
__device__ __forceinline__ float sig2(float x) {
    return __builtin_amdgcn_rcpf(1.0f + __builtin_amdgcn_exp2f(-x));
}
__device__ __forceinline__ float tanh2(float x2) {
    return 1.0f - 2.0f * __builtin_amdgcn_rcpf(__builtin_amdgcn_exp2f(x2) + 1.0f);
}

// ---------------------------------------------------------------------------
// Alias-proof half-broadcast (proven R10): early-clobber outputs guarantee
// distinct registers; after the swap, lo = low-half value broadcast to all
// lanes, hi = high-half value broadcast to all lanes.
// ---------------------------------------------------------------------------
__device__ __forceinline__ void half_bcast(float acc, float& lo, float& hi) {
    asm("v_mov_b32 %0, %2\n\t"
        "v_mov_b32 %1, %2\n\t"
        "v_permlane32_swap_b32 %0, %1"
        : "=&v"(lo), "=&v"(hi)
        : "v"(acc));
}

// ---------------------------------------------------------------------------
// Kernel 2: LSTM recurrence. One sequence per wave (512 waves, 2 waves/CU).
// R10-proven step body. SINGLE DELTA vs R10: xp loads are batched per 8-step
// block (phase A) into registers, so the 8-step compute phase (B) contains
// zero memory operations -> the per-step lgkmcnt wait disappears; the one
// wait per block lands in the rotate phase (D), off the dependence chain.
// ---------------------------------------------------------------------------
__global__ __launch_bounds__(64)
__attribute__((amdgpu_waves_per_eu(1, 1)))
void lstm_rec(
    const int*   __restrict__ tokens,   // [B][T]
    const float* __restrict__ w_hh,     // [128][32]
    const float* __restrict__ proj,     // [128][128], pre-scaled
    float*       __restrict__ h_out)    // [B*T][32]
{
    const int b    = blockIdx.x;
    const int lane = threadIdx.x;      // 0..63

    __shared__ float sproj[VOCAB * G4];   // 64 KB

    // ---- stage proj into LDS (once) ----
    {
        const float4* src = (const float4*)proj;
        float4*       dst = (float4*)sproj;
#pragma unroll 4
        for (int i = 0; i < (VOCAB * G4 / 4) / 64; ++i)
            dst[i * 64 + lane] = src[i * 64 + lane];
    }

    // ---- recurrent weights: 2 gate rows per lane, pre-scaled, pinned ----
    const float sc1 = (lane < 32) ? (2.0f * LOG2E) : LOG2E;
    float w0[HID], w1[HID];
#pragma unroll
    for (int j = 0; j < HID; ++j) {
        w0[j] = w_hh[lane * HID + j] * LOG2E;
        w1[j] = w_hh[(lane + 64) * HID + j] * sc1;
    }
#pragma unroll
    for (int j = 0; j < HID; ++j) {
        asm volatile("" : "+v"(w0[j]), "+v"(w1[j]));   // non-rematerializable
    }

    // ---- all 512 tokens of this sequence in lane registers ----
    // lane l holds tok[l*8 .. l*8+7]
    const int* tok = tokens + b * SEQ;
    int tv[KB];
    {
        int4 a = ((const int4*)tok)[lane * 2];
        int4 d = ((const int4*)tok)[lane * 2 + 1];
        tv[0] = a.x; tv[1] = a.y; tv[2] = a.z; tv[3] = a.w;
        tv[4] = d.x; tv[5] = d.y; tv[6] = d.z; tv[7] = d.w;
    }

    __syncthreads();

    float h = 0.0f, c = 0.0f;
    float* hp = h_out + (size_t)b * SEQ * HID + lane;   // lanes<32 store
    float hsave[KB];

    // xp double buffer in registers: xc = current block, xn = next block.
    // Block t0 covers steps t0..t0+7; its 8 tokens all live in lane t0>>3,
    // slots 0..7 (t0 is a multiple of 8).
    float xc0[KB], xc1[KB];

    // prologue: load block 0 (tokens in lane 0)
#pragma unroll
    for (int k = 0; k < KB; ++k) {
        int tk = __builtin_amdgcn_readlane(tv[k], 0);
        xc0[k] = sproj[tk * G4 + lane];
        xc1[k] = sproj[tk * G4 + 64 + lane];
    }

    for (int t0 = 0; t0 < SEQ; t0 += KB) {
        // ---- phase A: issue next block's 16 ds_reads (wrap to 0 at tail) ----
        const int nb = t0 + KB;
        const int ln = (nb < SEQ) ? (nb >> 3) : 0;   // uniform lane index
        float xn0[KB], xn1[KB];
#pragma unroll
        for (int k = 0; k < KB; ++k) {
            int tk = __builtin_amdgcn_readlane(tv[k], ln);
            xn0[k] = sproj[tk * G4 + lane];
            xn1[k] = sproj[tk * G4 + 64 + lane];
        }
        __builtin_amdgcn_sched_barrier(0);   // loads may not sink below here

        // ---- phase B: 8 recurrence steps, pure register compute ----
#pragma unroll
        for (int k = 0; k < KB; ++k) {
            float s0 = xc0[k], s1 = 0.0f, s2 = 0.0f, s3 = 0.0f;  // row lane
            float u0 = xc1[k], u1 = 0.0f, u2 = 0.0f, u3 = 0.0f;  // row lane+64
            unsigned hb = __float_as_uint(h);
#pragma unroll
            for (int j = 0; j < HID; j += 4) {
                float h0 = __uint_as_float(__builtin_amdgcn_readlane(hb, j));
                float h1 = __uint_as_float(__builtin_amdgcn_readlane(hb, j + 1));
                float h2 = __uint_as_float(__builtin_amdgcn_readlane(hb, j + 2));
                float h3 = __uint_as_float(__builtin_amdgcn_readlane(hb, j + 3));
                s0 = fmaf(h0, w0[j],     s0);
                s1 = fmaf(h1, w0[j + 1], s1);
                s2 = fmaf(h2, w0[j + 2], s2);
                s3 = fmaf(h3, w0[j + 3], s3);
                u0 = fmaf(h0, w1[j],     u0);
                u1 = fmaf(h1, w1[j + 1], u1);
                u2 = fmaf(h2, w1[j + 2], u2);
                u3 = fmaf(h3, w1[j + 3], u3);
            }
            float acc0 = (s0 + s1) + (s2 + s3);  // i (lo lanes) | f (hi lanes)
            float acc1 = (u0 + u1) + (u2 + u3);  // g (lo, *2log2e) | o (hi)

            // ---- alias-proof half broadcast: iv/gv = lo, fv/ov = hi ----
            float iv, fv, gv, ov;
            half_bcast(acc0, iv, fv);
            half_bcast(acc1, gv, ov);

            // ---- nonlinearities (exp2-domain, hw rcp) ----
            c = sig2(fv) * c + sig2(iv) * tanh2(gv);
            h = sig2(ov) * tanh2(c * (2.0f * LOG2E));

            hsave[k] = h;
        }

        // ---- phase C: flush h stores (no vmcnt wait inside the loop) ----
        if (lane < 32) {
#pragma unroll
            for (int k = 0; k < KB; ++k)
                hp[(size_t)(t0 + k) * HID] = hsave[k];
        }

        // ---- phase D: rotate next block into current (lgkm wait lands here) ----
#pragma unroll
        for (int k = 0; k < KB; ++k) {
            xc0[k] = xn0[k];
            xc1[k] = xn1[k];
        }
    }
}

// ---------------------------------------------------------------------------
// Kernel 3: logits[pos][v] = h[pos] . w_out[v] + b_out[v]   (R1-R10 proven)
// ---------------------------------------------------------------------------
#define POS_PER_WAVE 16

__global__ __launch_bounds__(256) void out_proj(
    const float* __restrict__ h,      // [B*T][32]
    const float* __restrict__ w_out,  // [128][32]
    const float* __restrict__ b_out,  // [128]
    float*       __restrict__ out)    // [B*T][128]
{
    const int gtid = blockIdx.x * blockDim.x + threadIdx.x;
    const int wave = gtid >> 6;
    const int lane = threadIdx.x & 63;

    float wv0[HID], wv1[HID];
#pragma unroll
    for (int j = 0; j < HID; ++j) {
        wv0[j] = w_out[lane * HID + j];
        wv1[j] = w_out[(lane + 64) * HID + j];
    }
    const float bb0 = b_out[lane];
    const float bb1 = b_out[lane + 64];

    int pos0 = wave * POS_PER_WAVE;
    for (int p = 0; p < POS_PER_WAVE; ++p) {
        int pos = __builtin_amdgcn_readfirstlane(pos0 + p);
        const float* hp = h + (size_t)pos * HID;
        float a0 = bb0, a1 = bb1;
#pragma unroll
        for (int j4 = 0; j4 < HID / 4; ++j4) {
            float4 hv = *reinterpret_cast<const float4*>(hp + 4 * j4);
            a0 = fmaf(hv.x, wv0[4 * j4 + 0], a0);
            a1 = fmaf(hv.x, wv1[4 * j4 + 0], a1);
            a0 = fmaf(hv.y, wv0[4 * j4 + 1], a0);
            a1 = fmaf(hv.y, wv1[4 * j4 + 1], a1);
            a0 = fmaf(hv.z, wv0[4 * j4 + 2], a0);
            a1 = fmaf(hv.z, wv1[4 * j4 + 2], a1);
            a0 = fmaf(hv.w, wv0[4 * j4 + 3], a0);
            a1 = fmaf(hv.w, wv1[4 * j4 + 3], a1);
        }
        out[(size_t)pos * VOCAB + lane]      = a0;
        out[(size_t)pos * VOCAB + 64 + lane] = a1;
    }
}

// ---------------------------------------------------------------------------
extern "C" void kernel_launch(void* const* d_in, const int* in_sizes, int n_in,
                              void* d_out, int out_size, void* d_ws, size_t ws_size,
                              hipStream_t stream) {
    const int*   tokens = (const int*)  d_in[0];
    const float* emb    = (const float*)d_in[1];
    const float* w_ih   = (const float*)d_in[2];
    const float* w_hh   = (const float*)d_in[3];
    const float* b_ih   = (const float*)d_in[4];
    const float* b_hh   = (const float*)d_in[5];
    const float* w_out  = (const float*)d_in[6];
    const float* b_out  = (const float*)d_in[7];
    float*       out    = (float*)d_out;

    float* proj = (float*)d_ws;
    float* hbuf = (float*)((char*)d_ws + VOCAB * G4 * sizeof(float));

    build_proj<<<(VOCAB * G4) / 256, 256, 0, stream>>>(emb, w_ih, b_ih, b_hh, proj);

    lstm_rec<<<BATCH, 64, 0, stream>>>(tokens, w_hh, proj, hbuf);

    const int total_pos = BATCH * SEQ;                    // 262144
    const int waves     = total_pos / POS_PER_WAVE;       // 16384
    out_proj<<<waves / 4, 256, 0, stream>>>(hbuf, w_out, b_out, out);
}